// Round 4
// baseline (12614.120 us; speedup 1.0000x reference)
//
#include <hip/hip_runtime.h>
#include <hip/hip_bf16.h>

// SimpleLSTM: persistent cooperative kernel, 64 WGs x 256 threads.
// WG g owns h-columns [8g, 8g+8) -> 32 gate rows. W slice lives in VGPRs (bf16).
// waves 0,1 (kh=0): x-half MFMA (independent of h, overlaps barrier wait)
// waves 2,3 (kh=1): spin on device barrier, then h-half MFMA.
// R2 change: NO __threadfence (device fences nuke per-XCD L2 -> 6x over-fetch,
// 19us/step). All cross-WG communicated data (h double buffer, barrier slots)
// uses relaxed AGENT-scope atomics (sc0 sc1: bypass L1/L2, straight to MALL).
// Ordering: __syncthreads() drains vmcnt(0) in every wave before tid0's slot
// release store; reader spins then loads h via agent atomics.

#define B_ 64
#define T_ 1024
#define I_ 512
#define H_ 512
#define NWG 64

typedef __attribute__((ext_vector_type(8))) short bf16x8;
typedef __attribute__((ext_vector_type(4))) float f32x4;

__device__ __forceinline__ unsigned cvt_pk_bf16(float lo, float hi) {
  unsigned r;
  asm volatile("v_cvt_pk_bf16_f32 %0, %1, %2" : "=v"(r) : "v"(lo), "v"(hi));
  return r;
}

__device__ __forceinline__ float sigf(float x) { return 1.0f / (1.0f + __expf(-x)); }
// NaN-safe tanh: saturates to +/-1 for large |x|
__device__ __forceinline__ float tanh_fast(float x) { return 1.0f - 2.0f / (__expf(2.0f * x) + 1.0f); }

__global__ __launch_bounds__(256, 1) void lstm_seq(
    const float* __restrict__ x, const float* __restrict__ Wih,
    const float* __restrict__ Whh, const float* __restrict__ bih,
    const float* __restrict__ bhh, float* __restrict__ out,
    unsigned* __restrict__ slots, unsigned short* __restrict__ hbuf)
{
  __shared__ float part[32 * 65];       // gate partials/gates: [vrow][batch] pitch 65
  const int tid  = threadIdx.x;
  const int wg   = blockIdx.x;          // 0..63
  const int wave = tid >> 6;            // 0..3
  const int lane = tid & 63;
  const int mh   = wave & 1;            // batch half (rows mh*32..mh*32+31)
  const int kh   = wave >> 1;           // 0: x-half of K, 1: h-half of K
  const int l15  = lane & 15;
  const int lg   = lane >> 4;           // 0..3

  // ---- load this wave's W slice into registers as bf16 (once) ----
  // virtual gate row v in [0,32): q=v>>3 (i,f,g,o), col = wg*8 + (v&7)
  bf16x8 wreg[2][16];                   // [n-tile][k-tile]
  {
    const float* Wsrc = (kh == 0) ? Wih : Whh;
    #pragma unroll
    for (int nt = 0; nt < 2; ++nt) {
      const int v = nt * 16 + l15;
      const int grow = (v >> 3) * 512 + wg * 8 + (v & 7);
      #pragma unroll
      for (int kt = 0; kt < 16; ++kt) {
        const float* p = Wsrc + (size_t)grow * 512 + kt * 32 + lg * 8;
        union { bf16x8 v8; unsigned u[4]; } wv;
        #pragma unroll
        for (int q = 0; q < 4; ++q) wv.u[q] = cvt_pk_bf16(p[2*q], p[2*q+1]);
        wreg[nt][kt] = wv.v8;
      }
    }
  }
  float biasv[2];
  #pragma unroll
  for (int nt = 0; nt < 2; ++nt) {
    const int v = nt * 16 + l15;
    const int grow = (v >> 3) * 512 + wg * 8 + (v & 7);
    biasv[nt] = bih[grow] + bhh[grow];
  }

  // elementwise state: thread handles batch bq, columns {2cp, 2cp+1}
  const int bq = tid >> 2;              // 0..63
  const int cp = tid & 3;               // col pair 0..3
  float cst[2] = {0.f, 0.f};

  for (int t = 0; t < T_; ++t) {
    f32x4 acc[2][2] = {};               // [m-tile][n-tile]
    if (kh == 0) {
      // ---- x-half: A[b][k] = x[b][t][k] (fp32 -> bf16 in-reg) ----
      const float* xt = x + (size_t)t * I_;
      #pragma unroll
      for (int kt = 0; kt < 16; ++kt) {
        #pragma unroll
        for (int mt = 0; mt < 2; ++mt) {
          const int b = mh * 32 + mt * 16 + l15;
          const float* p = xt + (size_t)b * ((size_t)T_ * I_) + kt * 32 + lg * 8;
          f32x4 f0 = *(const f32x4*)p;
          f32x4 f1 = *(const f32x4*)(p + 4);
          union { bf16x8 v8; unsigned u[4]; } av;
          av.u[0] = cvt_pk_bf16(f0.x, f0.y);
          av.u[1] = cvt_pk_bf16(f0.z, f0.w);
          av.u[2] = cvt_pk_bf16(f1.x, f1.y);
          av.u[3] = cvt_pk_bf16(f1.z, f1.w);
          #pragma unroll
          for (int nt = 0; nt < 2; ++nt)
            acc[mt][nt] = __builtin_amdgcn_mfma_f32_16x16x32_bf16(av.v8, wreg[nt][kt], acc[mt][nt], 0, 0, 0);
        }
      }
      // write x partials to LDS
      #pragma unroll
      for (int mt = 0; mt < 2; ++mt)
        #pragma unroll
        for (int nt = 0; nt < 2; ++nt) {
          const int v = nt * 16 + l15;
          const int bb = mh * 32 + mt * 16 + lg * 4;
          #pragma unroll
          for (int r = 0; r < 4; ++r) part[v * 65 + bb + r] = acc[mt][nt][r];
        }
    } else if (t > 0) {
      // ---- wait for all WGs to finish step t-1 (h_t visible at MALL) ----
      const unsigned tgt = (unsigned)t;
      int guard = 0;
      for (;;) {
        unsigned sv = __hip_atomic_load(&slots[lane], __ATOMIC_RELAXED, __HIP_MEMORY_SCOPE_AGENT);
        if (__all((int)(sv >= tgt))) break;
        if (++guard > (1 << 22)) break;   // safety valve against hang
        __builtin_amdgcn_s_sleep(1);
      }
      // compiler fence: don't hoist h loads above the spin
      asm volatile("" ::: "memory");
      __builtin_amdgcn_sched_barrier(0);
      const unsigned long long* h64 =
          (const unsigned long long*)(hbuf + (size_t)(t & 1) * (B_ * H_));
      #pragma unroll
      for (int kt = 0; kt < 16; ++kt) {
        #pragma unroll
        for (int mt = 0; mt < 2; ++mt) {
          const int b = mh * 32 + mt * 16 + l15;
          const size_t e = ((size_t)b * H_ + kt * 32 + lg * 8) >> 2;  // u64 index
          union { bf16x8 v8; unsigned long long q[2]; } av;
          av.q[0] = __hip_atomic_load(&h64[e],     __ATOMIC_RELAXED, __HIP_MEMORY_SCOPE_AGENT);
          av.q[1] = __hip_atomic_load(&h64[e + 1], __ATOMIC_RELAXED, __HIP_MEMORY_SCOPE_AGENT);
          #pragma unroll
          for (int nt = 0; nt < 2; ++nt)
            acc[mt][nt] = __builtin_amdgcn_mfma_f32_16x16x32_bf16(av.v8, wreg[nt][kt], acc[mt][nt], 0, 0, 0);
        }
      }
    }
    __syncthreads();
    if (kh == 1) {
      // gates = x-part + h-acc + bias (in place)
      #pragma unroll
      for (int mt = 0; mt < 2; ++mt)
        #pragma unroll
        for (int nt = 0; nt < 2; ++nt) {
          const int v = nt * 16 + l15;
          const int bb = mh * 32 + mt * 16 + lg * 4;
          #pragma unroll
          for (int r = 0; r < 4; ++r)
            part[v * 65 + bb + r] += acc[mt][nt][r] + biasv[nt];
        }
    }
    __syncthreads();
    // ---- elementwise LSTM cell update: thread = (batch bq, cols 2cp..2cp+1) ----
    {
      unsigned* hdst32 = (unsigned*)(hbuf + (size_t)((t + 1) & 1) * (B_ * H_));
      float hv[2];
      #pragma unroll
      for (int d = 0; d < 2; ++d) {
        const int nl = 2 * cp + d;
        float gi = part[(0 * 8 + nl) * 65 + bq];
        float gf = part[(1 * 8 + nl) * 65 + bq];
        float gg = part[(2 * 8 + nl) * 65 + bq];
        float go = part[(3 * 8 + nl) * 65 + bq];
        float c = sigf(gf) * cst[d] + sigf(gi) * tanh_fast(gg);
        cst[d] = c;
        hv[d] = sigf(go) * tanh_fast(c);
      }
      if (t == T_ - 1) {
        out[(size_t)bq * H_ + wg * 8 + 2 * cp]     = hv[0];
        out[(size_t)bq * H_ + wg * 8 + 2 * cp + 1] = hv[1];
      } else {
        const unsigned pk = cvt_pk_bf16(hv[0], hv[1]);
        __hip_atomic_store(&hdst32[((size_t)bq * H_ + wg * 8 + 2 * cp) >> 1], pk,
                           __ATOMIC_RELAXED, __HIP_MEMORY_SCOPE_AGENT);
      }
    }
    // __syncthreads drains vmcnt(0) in every wave -> all h stores are at the
    // coherence point before tid0's slot release below.
    __syncthreads();
    if (tid == 0 && t < T_ - 1) {
      __hip_atomic_store(&slots[wg], (unsigned)(t + 1), __ATOMIC_RELAXED, __HIP_MEMORY_SCOPE_AGENT);
    }
  }
}

extern "C" void kernel_launch(void* const* d_in, const int* in_sizes, int n_in,
                              void* d_out, int out_size, void* d_ws, size_t ws_size,
                              hipStream_t stream) {
  const float* x   = (const float*)d_in[0];
  const float* Wih = (const float*)d_in[1];
  const float* Whh = (const float*)d_in[2];
  const float* bih = (const float*)d_in[3];
  const float* bhh = (const float*)d_in[4];
  float* out = (float*)d_out;

  // ws layout: [0,1024): barrier slots (64 x u32, zeroed each launch)
  //            [1024, 1024+256K): h double buffer, bf16 [2][64][512]
  unsigned* slots = (unsigned*)d_ws;
  unsigned short* hbuf = (unsigned short*)((char*)d_ws + 1024);

  hipMemsetAsync(d_ws, 0, 1024, stream);
  lstm_seq<<<NWG, 256, 0, stream>>>(x, Wih, Whh, bih, bhh, out, slots, hbuf);
}

// Round 5
// 12596.214 us; speedup vs baseline: 1.0014x; 1.0014x over previous
//
#include <hip/hip_runtime.h>
#include <hip/hip_bf16.h>

// SimpleLSTM: persistent cooperative kernel, 64 WGs x 256 threads.
// WG g owns h-columns [8g, 8g+8) -> 32 gate rows. W slice lives in VGPRs (bf16).
// waves 0,1 (kh=0): x-half MFMA (independent of h, overlaps barrier wait)
// waves 2,3 (kh=1): spin on device barrier, then h-half MFMA.
// R2 change: NO __threadfence (device fences nuke per-XCD L2 -> 6x over-fetch,
// 19us/step). All cross-WG communicated data (h double buffer, barrier slots)
// uses relaxed AGENT-scope atomics (sc0 sc1: bypass L1/L2, straight to MALL).
// Ordering: __syncthreads() drains vmcnt(0) in every wave before tid0's slot
// release store; reader spins then loads h via agent atomics.

#define B_ 64
#define T_ 1024
#define I_ 512
#define H_ 512
#define NWG 64

typedef __attribute__((ext_vector_type(8))) short bf16x8;
typedef __attribute__((ext_vector_type(4))) float f32x4;

__device__ __forceinline__ unsigned cvt_pk_bf16(float lo, float hi) {
  unsigned r;
  asm volatile("v_cvt_pk_bf16_f32 %0, %1, %2" : "=v"(r) : "v"(lo), "v"(hi));
  return r;
}

__device__ __forceinline__ float sigf(float x) { return 1.0f / (1.0f + __expf(-x)); }
// NaN-safe tanh: saturates to +/-1 for large |x|
__device__ __forceinline__ float tanh_fast(float x) { return 1.0f - 2.0f / (__expf(2.0f * x) + 1.0f); }

__global__ __launch_bounds__(256, 1) void lstm_seq(
    const float* __restrict__ x, const float* __restrict__ Wih,
    const float* __restrict__ Whh, const float* __restrict__ bih,
    const float* __restrict__ bhh, float* __restrict__ out,
    unsigned* __restrict__ slots, unsigned short* __restrict__ hbuf)
{
  __shared__ float part[32 * 65];       // gate partials/gates: [vrow][batch] pitch 65
  const int tid  = threadIdx.x;
  const int wg   = blockIdx.x;          // 0..63
  const int wave = tid >> 6;            // 0..3
  const int lane = tid & 63;
  const int mh   = wave & 1;            // batch half (rows mh*32..mh*32+31)
  const int kh   = wave >> 1;           // 0: x-half of K, 1: h-half of K
  const int l15  = lane & 15;
  const int lg   = lane >> 4;           // 0..3

  // ---- load this wave's W slice into registers as bf16 (once) ----
  // virtual gate row v in [0,32): q=v>>3 (i,f,g,o), col = wg*8 + (v&7)
  bf16x8 wreg[2][16];                   // [n-tile][k-tile]
  {
    const float* Wsrc = (kh == 0) ? Wih : Whh;
    #pragma unroll
    for (int nt = 0; nt < 2; ++nt) {
      const int v = nt * 16 + l15;
      const int grow = (v >> 3) * 512 + wg * 8 + (v & 7);
      #pragma unroll
      for (int kt = 0; kt < 16; ++kt) {
        const float* p = Wsrc + (size_t)grow * 512 + kt * 32 + lg * 8;
        union { bf16x8 v8; unsigned u[4]; } wv;
        #pragma unroll
        for (int q = 0; q < 4; ++q) wv.u[q] = cvt_pk_bf16(p[2*q], p[2*q+1]);
        wreg[nt][kt] = wv.v8;
      }
    }
  }
  float biasv[2];
  #pragma unroll
  for (int nt = 0; nt < 2; ++nt) {
    const int v = nt * 16 + l15;
    const int grow = (v >> 3) * 512 + wg * 8 + (v & 7);
    biasv[nt] = bih[grow] + bhh[grow];
  }

  // elementwise state: thread handles batch bq, columns {2cp, 2cp+1}
  const int bq = tid >> 2;              // 0..63
  const int cp = tid & 3;               // col pair 0..3
  float cst[2] = {0.f, 0.f};

  for (int t = 0; t < T_; ++t) {
    f32x4 acc[2][2] = {};               // [m-tile][n-tile]
    if (kh == 0) {
      // ---- x-half: A[b][k] = x[b][t][k] (fp32 -> bf16 in-reg) ----
      const float* xt = x + (size_t)t * I_;
      #pragma unroll
      for (int kt = 0; kt < 16; ++kt) {
        #pragma unroll
        for (int mt = 0; mt < 2; ++mt) {
          const int b = mh * 32 + mt * 16 + l15;
          const float* p = xt + (size_t)b * ((size_t)T_ * I_) + kt * 32 + lg * 8;
          f32x4 f0 = *(const f32x4*)p;
          f32x4 f1 = *(const f32x4*)(p + 4);
          union { bf16x8 v8; unsigned u[4]; } av;
          av.u[0] = cvt_pk_bf16(f0.x, f0.y);
          av.u[1] = cvt_pk_bf16(f0.z, f0.w);
          av.u[2] = cvt_pk_bf16(f1.x, f1.y);
          av.u[3] = cvt_pk_bf16(f1.z, f1.w);
          #pragma unroll
          for (int nt = 0; nt < 2; ++nt)
            acc[mt][nt] = __builtin_amdgcn_mfma_f32_16x16x32_bf16(av.v8, wreg[nt][kt], acc[mt][nt], 0, 0, 0);
        }
      }
      // write x partials to LDS
      #pragma unroll
      for (int mt = 0; mt < 2; ++mt)
        #pragma unroll
        for (int nt = 0; nt < 2; ++nt) {
          const int v = nt * 16 + l15;
          const int bb = mh * 32 + mt * 16 + lg * 4;
          #pragma unroll
          for (int r = 0; r < 4; ++r) part[v * 65 + bb + r] = acc[mt][nt][r];
        }
    } else if (t > 0) {
      // ---- wait for all WGs to finish step t-1 (h_t visible at MALL) ----
      const unsigned tgt = (unsigned)t;
      int guard = 0;
      for (;;) {
        unsigned sv = __hip_atomic_load(&slots[lane], __ATOMIC_RELAXED, __HIP_MEMORY_SCOPE_AGENT);
        if (__all((int)(sv >= tgt))) break;
        if (++guard > (1 << 22)) break;   // safety valve against hang
        __builtin_amdgcn_s_sleep(1);
      }
      // compiler fence: don't hoist h loads above the spin
      asm volatile("" ::: "memory");
      __builtin_amdgcn_sched_barrier(0);
      const unsigned long long* h64 =
          (const unsigned long long*)(hbuf + (size_t)(t & 1) * (B_ * H_));
      #pragma unroll
      for (int kt = 0; kt < 16; ++kt) {
        #pragma unroll
        for (int mt = 0; mt < 2; ++mt) {
          const int b = mh * 32 + mt * 16 + l15;
          const size_t e = ((size_t)b * H_ + kt * 32 + lg * 8) >> 2;  // u64 index
          union { bf16x8 v8; unsigned long long q[2]; } av;
          av.q[0] = __hip_atomic_load(&h64[e],     __ATOMIC_RELAXED, __HIP_MEMORY_SCOPE_AGENT);
          av.q[1] = __hip_atomic_load(&h64[e + 1], __ATOMIC_RELAXED, __HIP_MEMORY_SCOPE_AGENT);
          #pragma unroll
          for (int nt = 0; nt < 2; ++nt)
            acc[mt][nt] = __builtin_amdgcn_mfma_f32_16x16x32_bf16(av.v8, wreg[nt][kt], acc[mt][nt], 0, 0, 0);
        }
      }
    }
    __syncthreads();
    if (kh == 1) {
      // gates = x-part + h-acc + bias (in place)
      #pragma unroll
      for (int mt = 0; mt < 2; ++mt)
        #pragma unroll
        for (int nt = 0; nt < 2; ++nt) {
          const int v = nt * 16 + l15;
          const int bb = mh * 32 + mt * 16 + lg * 4;
          #pragma unroll
          for (int r = 0; r < 4; ++r)
            part[v * 65 + bb + r] += acc[mt][nt][r] + biasv[nt];
        }
    }
    __syncthreads();
    // ---- elementwise LSTM cell update: thread = (batch bq, cols 2cp..2cp+1) ----
    {
      unsigned* hdst32 = (unsigned*)(hbuf + (size_t)((t + 1) & 1) * (B_ * H_));
      float hv[2];
      #pragma unroll
      for (int d = 0; d < 2; ++d) {
        const int nl = 2 * cp + d;
        float gi = part[(0 * 8 + nl) * 65 + bq];
        float gf = part[(1 * 8 + nl) * 65 + bq];
        float gg = part[(2 * 8 + nl) * 65 + bq];
        float go = part[(3 * 8 + nl) * 65 + bq];
        float c = sigf(gf) * cst[d] + sigf(gi) * tanh_fast(gg);
        cst[d] = c;
        hv[d] = sigf(go) * tanh_fast(c);
      }
      if (t == T_ - 1) {
        out[(size_t)bq * H_ + wg * 8 + 2 * cp]     = hv[0];
        out[(size_t)bq * H_ + wg * 8 + 2 * cp + 1] = hv[1];
      } else {
        const unsigned pk = cvt_pk_bf16(hv[0], hv[1]);
        __hip_atomic_store(&hdst32[((size_t)bq * H_ + wg * 8 + 2 * cp) >> 1], pk,
                           __ATOMIC_RELAXED, __HIP_MEMORY_SCOPE_AGENT);
      }
    }
    // __syncthreads drains vmcnt(0) in every wave -> all h stores are at the
    // coherence point before tid0's slot release below.
    __syncthreads();
    if (tid == 0 && t < T_ - 1) {
      __hip_atomic_store(&slots[wg], (unsigned)(t + 1), __ATOMIC_RELAXED, __HIP_MEMORY_SCOPE_AGENT);
    }
  }
}

extern "C" void kernel_launch(void* const* d_in, const int* in_sizes, int n_in,
                              void* d_out, int out_size, void* d_ws, size_t ws_size,
                              hipStream_t stream) {
  const float* x   = (const float*)d_in[0];
  const float* Wih = (const float*)d_in[1];
  const float* Whh = (const float*)d_in[2];
  const float* bih = (const float*)d_in[3];
  const float* bhh = (const float*)d_in[4];
  float* out = (float*)d_out;

  // ws layout: [0,1024): barrier slots (64 x u32, zeroed each launch)
  //            [1024, 1024+256K): h double buffer, bf16 [2][64][512]
  unsigned* slots = (unsigned*)d_ws;
  unsigned short* hbuf = (unsigned short*)((char*)d_ws + 1024);

  hipMemsetAsync(d_ws, 0, 1024, stream);
  lstm_seq<<<NWG, 256, 0, stream>>>(x, Wih, Whh, bih, bhh, out, slots, hbuf);
}